// Round 4
// baseline (748.776 us; speedup 1.0000x reference)
//
#include <hip/hip_runtime.h>

typedef _Float16 f16;
typedef _Float16 f16x2 __attribute__((ext_vector_type(2)));
typedef _Float16 f16x4 __attribute__((ext_vector_type(4)));
typedef _Float16 f16x8 __attribute__((ext_vector_type(8)));
typedef float f32x4 __attribute__((ext_vector_type(4)));

#define KM 0.1f   // DT * TAU_MEM_INV
#define KS 0.8f   // 1 - DT * TAU_SYN_INV
#define AS1 __attribute__((address_space(1)))
#define AS3 __attribute__((address_space(3)))

// ---------- merged weight prep: fp32 -> f16 hi + f16 (lo*4096), zero-padded ----------
struct PrepArgs {
  const float* W[6];
  f16* hi[6];
  f16* lo[6];
  int Nr[6], Kr[6], Kp[6];
  int boff[7];  // per-layer block offsets
};

__global__ void prep_w_all(PrepArgs a) {
  int blk = blockIdx.x;
  int k = 0;
#pragma unroll
  for (int j = 0; j < 5; ++j) k += (blk >= a.boff[j + 1]) ? 1 : 0;
  int i = (blk - a.boff[k]) * 256 + threadIdx.x;
  int Kp = a.Kp[k];
  int kp4 = Kp >> 2;
  int total4 = (a.Nr[k] == 2000 ? 2048 : (a.Nr[k] == 1500 ? 1536 : (a.Nr[k] == 1000 ? 1024 : (a.Nr[k] == 500 ? 512 : 128)))) * kp4;
  if (i >= total4) return;
  int o = i / kp4, f = (i - o * kp4) << 2;
  float w[4] = {0.f, 0.f, 0.f, 0.f};
  if (o < a.Nr[k] && f < a.Kr[k]) {  // Kr % 4 == 0 -> float4 fully in-range
    float4 t = *(const float4*)&a.W[k][(size_t)o * a.Kr[k] + f];
    w[0] = t.x; w[1] = t.y; w[2] = t.z; w[3] = t.w;
  }
  f16x4 h4, l4;
#pragma unroll
  for (int e = 0; e < 4; ++e) {
    f16 h = (f16)w[e];
    float hf = (float)h;
    if (__builtin_fabsf(hf) < 6.103515625e-05f) { h = (f16)0.f; hf = 0.f; }
    h4[e] = h;
    l4[e] = (f16)((w[e] - hf) * 4096.0f);
  }
  *(f16x4*)&a.hi[k][(size_t)o * Kp + f] = h4;
  *(f16x4*)&a.lo[k][(size_t)o * Kp + f] = l4;
}

// ---------- encoder + LIF0, 2 features per thread ----------
__global__ void enc_lif0(const float* __restrict__ img, f16* __restrict__ S0) {
  int idx = blockIdx.x * 256 + threadIdx.x;
  if (idx >= 128 * 6016) return;
  int b = idx / 6016, f = (idx - b * 6016) << 1;
  float x0 = 0.f, x1 = 0.f;
  if (f < 12000) {
    float2 t = *(const float2*)&img[b * 12000 + f];
    x0 = t.x; x1 = t.y;
  }
  float ve0 = 0.f, vl0 = 0.f, il0 = 0.f;
  float ve1 = 0.f, vl1 = 0.f, il1 = 0.f;
  size_t base = (size_t)b * 12032 + f;
  for (int t = 0; t < 32; ++t) {
    ve0 = ve0 + KM * (x0 - ve0);
    ve1 = ve1 + KM * (x1 - ve1);
    float z0a = (ve0 > 1.0f) ? 1.f : 0.f;
    float z0b = (ve1 > 1.0f) ? 1.f : 0.f;
    ve0 -= z0a * ve0; ve1 -= z0b * ve1;
    float vd0 = vl0 + KM * (il0 - vl0), id0 = KS * il0;
    float vd1 = vl1 + KM * (il1 - vl1), id1 = KS * il1;
    float z1a = (vd0 > 1.0f) ? 1.f : 0.f;
    float z1b = (vd1 > 1.0f) ? 1.f : 0.f;
    vl0 = (1.f - z1a) * vd0; il0 = id0 + z0a;
    vl1 = (1.f - z1b) * vd1; il1 = id1 + z0b;
    f16x2 s; s[0] = (f16)z1a; s[1] = (f16)z1b;
    *(f16x2*)&S0[base + (size_t)t * (128 * 12032)] = s;
  }
}

// ---------- counted-vmcnt phased GEMM (T3+T4+T5): BM=256,BN=128,BK=64, 8 waves ----------
// Per K-tile: 2 kk-phases. Phase entry: s_waitcnt vmcnt(4) + s_barrier (drains oldest
// staged half across all waves; newest 4 loads stay in flight ACROSS the barrier).
// LDS halves are contiguous [256|128 rows][32 f16] with 4-slot XOR swizzle c^=(r&3);
// global source pre-swizzled (rule #21). Double-buffered, 128 KiB, 1 block/CU.
__launch_bounds__(512, 2)
__global__ void gemm_8ph(const f16* __restrict__ A, const f16* __restrict__ Bh,
                         const f16* __restrict__ Bl, float* __restrict__ C,
                         int Kp, int Np) {
  __shared__ f16 sA[2 * 2 * 256 * 32];   // 64 KiB: [buf][half][256][32]
  __shared__ f16 sBh[2 * 2 * 128 * 32];  // 32 KiB
  __shared__ f16 sBl[2 * 2 * 128 * 32];  // 32 KiB
  const int tid = threadIdx.x;
  const int lane = tid & 63;
  const int wave = tid >> 6;
  const int wr = wave >> 1;   // 0..3 over M (64 rows each)
  const int wc = wave & 1;    // 0..1 over N (64 cols each)

  const int nx = gridDim.x;
  const int flat = blockIdx.y * nx + blockIdx.x;
  const int cpx = (nx * gridDim.y) >> 3;
  const int id = (flat & 7) * cpx + (flat >> 3);
  const int m0 = (id / nx) * 256, n0 = (id % nx) * 128;

  f32x4 zero = {0.f, 0.f, 0.f, 0.f};
  f32x4 ah[4][4], al[4][4];
#pragma unroll
  for (int m = 0; m < 4; ++m)
#pragma unroll
    for (int n = 0; n < 4; ++n) { ah[m][n] = zero; al[m][n] = zero; }

  const f16* Abase = A + (size_t)m0 * Kp;
  const f16* Bhbase = Bh + (size_t)n0 * Kp;
  const f16* Blbase = Bl + (size_t)n0 * Kp;
  const int nkt = Kp >> 6;

  // 4 loads/thread per half-tile: A x2, Bh x1, Bl x1
#define STAGE_HALF(buf, kt, h)                                                          \
  do {                                                                                  \
    _Pragma("unroll")                                                                   \
    for (int j = 0; j < 2; ++j) {                                                       \
      int qq = j * 512 + tid;                                                           \
      int r = qq >> 2, s = qq & 3, c = s ^ (r & 3);                                     \
      __builtin_amdgcn_global_load_lds(                                                 \
          (const AS1 void*)(Abase + (size_t)r * Kp + (kt) * 64 + (h) * 32 + c * 8),     \
          (AS3 void*)(&sA[((buf) * 2 + (h)) * 8192 + qq * 8]), 16, 0, 0);               \
    }                                                                                   \
    {                                                                                   \
      int r = tid >> 2, s = tid & 3, c = s ^ (r & 3);                                   \
      size_t so = (size_t)r * Kp + (kt) * 64 + (h) * 32 + c * 8;                        \
      __builtin_amdgcn_global_load_lds((const AS1 void*)(Bhbase + so),                  \
          (AS3 void*)(&sBh[((buf) * 2 + (h)) * 4096 + tid * 8]), 16, 0, 0);             \
      __builtin_amdgcn_global_load_lds((const AS1 void*)(Blbase + so),                  \
          (AS3 void*)(&sBl[((buf) * 2 + (h)) * 4096 + tid * 8]), 16, 0, 0);             \
    }                                                                                   \
  } while (0)

#define COMPUTE_PHASE(buf, h)                                                           \
  do {                                                                                  \
    const int lr = lane & 15;                                                           \
    const int q = lane >> 4;                                                            \
    f16x8 af[4], bhf[4], blf[4];                                                        \
    _Pragma("unroll")                                                                   \
    for (int m = 0; m < 4; ++m) {                                                       \
      int R = wr * 64 + m * 16 + lr;                                                    \
      af[m] = *(const f16x8*)&sA[((buf) * 2 + (h)) * 8192 + R * 32 + ((q ^ (R & 3)) * 8)]; \
    }                                                                                   \
    _Pragma("unroll")                                                                   \
    for (int n = 0; n < 4; ++n) {                                                       \
      int R = wc * 64 + n * 16 + lr;                                                    \
      int off = ((buf) * 2 + (h)) * 4096 + R * 32 + ((q ^ (R & 3)) * 8);                \
      bhf[n] = *(const f16x8*)&sBh[off];                                                \
      blf[n] = *(const f16x8*)&sBl[off];                                                \
    }                                                                                   \
    __builtin_amdgcn_s_setprio(1);                                                      \
    _Pragma("unroll")                                                                   \
    for (int m = 0; m < 4; ++m)                                                         \
      _Pragma("unroll")                                                                 \
      for (int n = 0; n < 4; ++n) {                                                     \
        ah[m][n] = __builtin_amdgcn_mfma_f32_16x16x32_f16(af[m], bhf[n], ah[m][n], 0, 0, 0); \
        al[m][n] = __builtin_amdgcn_mfma_f32_16x16x32_f16(af[m], blf[n], al[m][n], 0, 0, 0); \
      }                                                                                 \
    __builtin_amdgcn_s_setprio(0);                                                      \
  } while (0)

#define PHASE_WAIT4() \
  do { asm volatile("s_waitcnt vmcnt(4)" ::: "memory"); \
       __builtin_amdgcn_s_barrier(); \
       __builtin_amdgcn_sched_barrier(0); } while (0)

  STAGE_HALF(0, 0, 0);
  STAGE_HALF(0, 0, 1);

  int cur = 0;
  for (int kt = 0; kt < nkt - 1; ++kt) {
    PHASE_WAIT4();                    // all waves' (t,h0) staged; (t,h1) may fly
    STAGE_HALF(cur ^ 1, kt + 1, 0);   // 4 loads -> in flight across next barrier
    COMPUTE_PHASE(cur, 0);
    PHASE_WAIT4();                    // drains (t,h1); (t+1,h0) stays in flight
    STAGE_HALF(cur ^ 1, kt + 1, 1);
    COMPUTE_PHASE(cur, 1);
    cur ^= 1;
  }
  // last tile (peeled): no further staging
  PHASE_WAIT4();
  COMPUTE_PHASE(cur, 0);
  asm volatile("s_waitcnt vmcnt(0)" ::: "memory");
  __builtin_amdgcn_s_barrier();
  __builtin_amdgcn_sched_barrier(0);
  COMPUTE_PHASE(cur, 1);
#undef STAGE_HALF
#undef COMPUTE_PHASE
#undef PHASE_WAIT4

  const int lr = lane & 15, lq = lane >> 4;
#pragma unroll
  for (int m = 0; m < 4; ++m)
#pragma unroll
    for (int n = 0; n < 4; ++n) {
      int col = n0 + wc * 64 + n * 16 + lr;
#pragma unroll
      for (int i = 0; i < 4; ++i) {
        int row = m0 + wr * 64 + m * 16 + lq * 4 + i;
        C[(size_t)row * Np + col] = ah[m][n][i] + 2.44140625e-4f * al[m][n][i];
      }
    }
}

// ---------- 128x128 4-wave GEMM (round-1 proven) for small layers ----------
__launch_bounds__(256, 2)
__global__ void gemm_hilo(const f16* __restrict__ A, const f16* __restrict__ Bh,
                          const f16* __restrict__ Bl, float* __restrict__ C,
                          int Kp, int Np) {
  __shared__ f16 sA[128 * 64];
  __shared__ f16 sBh[128 * 64];
  __shared__ f16 sBl[128 * 64];
  const int tid = threadIdx.x;
  const int lane = tid & 63;
  const int wave = tid >> 6;
  const int wr = wave >> 1, wc = wave & 1;

  const int nx = gridDim.x;
  const int flat = blockIdx.y * nx + blockIdx.x;
  const int cpx = (nx * gridDim.y) >> 3;
  const int id = (flat & 7) * cpx + (flat >> 3);
  const int m0 = (id / nx) * 128, n0 = (id % nx) * 128;

  f32x4 zero = {0.f, 0.f, 0.f, 0.f};
  f32x4 ah[4][4], al[4][4];
#pragma unroll
  for (int m = 0; m < 4; ++m)
#pragma unroll
    for (int n = 0; n < 4; ++n) { ah[m][n] = zero; al[m][n] = zero; }

  const int nkt = Kp >> 6;
  for (int kt = 0; kt < nkt; ++kt) {
    __syncthreads();
    const f16* Ab = A + (size_t)m0 * Kp + (size_t)kt * 64;
    const f16* Bhb = Bh + (size_t)n0 * Kp + (size_t)kt * 64;
    const f16* Blb = Bl + (size_t)n0 * Kp + (size_t)kt * 64;
#pragma unroll
    for (int j = 0; j < 4; ++j) {
      int q = j * 256 + tid;
      int r = q >> 3;
      int c0 = ((q & 7) ^ (r & 7)) * 8;
      __builtin_amdgcn_global_load_lds((const AS1 void*)(Ab + (size_t)r * Kp + c0),
                                       (AS3 void*)(&sA[q * 8]), 16, 0, 0);
      __builtin_amdgcn_global_load_lds((const AS1 void*)(Bhb + (size_t)r * Kp + c0),
                                       (AS3 void*)(&sBh[q * 8]), 16, 0, 0);
      __builtin_amdgcn_global_load_lds((const AS1 void*)(Blb + (size_t)r * Kp + c0),
                                       (AS3 void*)(&sBl[q * 8]), 16, 0, 0);
    }
    __syncthreads();
#pragma unroll
    for (int kk = 0; kk < 2; ++kk) {
      const int lr = lane & 15;
      const int hq = lane >> 4;
      f16x8 af[4], bhf[4], blf[4];
#pragma unroll
      for (int m = 0; m < 4; ++m) {
        int R = wr * 64 + m * 16 + lr;
        int ch = (kk * 4 + hq) ^ (R & 7);
        af[m] = *(const f16x8*)&sA[R * 64 + ch * 8];
      }
#pragma unroll
      for (int n = 0; n < 4; ++n) {
        int R = wc * 64 + n * 16 + lr;
        int ch = (kk * 4 + hq) ^ (R & 7);
        bhf[n] = *(const f16x8*)&sBh[R * 64 + ch * 8];
        blf[n] = *(const f16x8*)&sBl[R * 64 + ch * 8];
      }
#pragma unroll
      for (int m = 0; m < 4; ++m)
#pragma unroll
        for (int n = 0; n < 4; ++n) {
          ah[m][n] = __builtin_amdgcn_mfma_f32_16x16x32_f16(af[m], bhf[n], ah[m][n], 0, 0, 0);
          al[m][n] = __builtin_amdgcn_mfma_f32_16x16x32_f16(af[m], blf[n], al[m][n], 0, 0, 0);
        }
    }
  }
  const int lr = lane & 15, lq = lane >> 4;
#pragma unroll
  for (int m = 0; m < 4; ++m)
#pragma unroll
    for (int n = 0; n < 4; ++n) {
      int col = n0 + wc * 64 + n * 16 + lr;
#pragma unroll
      for (int i = 0; i < 4; ++i) {
        int row = m0 + wr * 64 + m * 16 + lq * 4 + i;
        C[(size_t)row * Np + col] = ah[m][n][i] + 2.44140625e-4f * al[m][n][i];
      }
    }
}

// ---------- LI_k + LIF_{k+1}, 2 neurons per thread ----------
__global__ void li_lif(const float* __restrict__ G, f16* __restrict__ Sn, int Np) {
  int np2 = Np >> 1;
  int idx = blockIdx.x * 256 + threadIdx.x;
  if (idx >= 128 * np2) return;
  int b = idx / np2, n = (idx - b * np2) << 1;
  size_t base = (size_t)b * Np + n;
  size_t stride = (size_t)128 * Np;
  float vL0 = 0.f, iL0 = 0.f, vF0 = 0.f, iF0 = 0.f;
  float vL1 = 0.f, iL1 = 0.f, vF1 = 0.f, iF1 = 0.f;
  for (int t = 0; t < 32; ++t) {
    float2 g = *(const float2*)&G[base + t * stride];
    float ij0 = iL0 + g.x, ij1 = iL1 + g.y;
    vL0 = vL0 + KM * (ij0 - vL0); iL0 = KS * ij0;
    vL1 = vL1 + KM * (ij1 - vL1); iL1 = KS * ij1;
    float vd0 = vF0 + KM * (iF0 - vF0), id0 = KS * iF0;
    float vd1 = vF1 + KM * (iF1 - vF1), id1 = KS * iF1;
    float z0 = (vd0 > 1.0f) ? 1.f : 0.f;
    float z1 = (vd1 > 1.0f) ? 1.f : 0.f;
    vF0 = (1.f - z0) * vd0; iF0 = id0 + vL0;
    vF1 = (1.f - z1) * vd1; iF1 = id1 + vL1;
    f16x2 s; s[0] = (f16)z0; s[1] = (f16)z1;
    *(f16x2*)&Sn[base + t * stride] = s;
  }
}

// ---------- LI5 scan + max over t + log_softmax ----------
__global__ void final_k(const float* __restrict__ G, float* __restrict__ out) {
  int b = blockIdx.x;
  int n = threadIdx.x;
  float vL = 0.f, iL = 0.f, mx = -3.4e38f;
  for (int t = 0; t < 32; ++t) {
    float g = G[(size_t)(t * 128 + b) * 128 + n];
    float ij = iL + g;
    vL = vL + KM * (ij - vL);
    iL = KS * ij;
    mx = fmaxf(mx, vL);
  }
  float v = (n < 10) ? mx : -3.4e38f;
  float M = v;
#pragma unroll
  for (int s = 1; s < 16; s <<= 1) M = fmaxf(M, __shfl_xor(M, s));
  float e = (n < 10) ? expf(v - M) : 0.f;
  float sum = e;
#pragma unroll
  for (int s = 1; s < 16; s <<= 1) sum += __shfl_xor(sum, s);
  if (n < 10) out[b * 10 + n] = v - M - logf(sum);
}

extern "C" void kernel_launch(void* const* d_in, const int* in_sizes, int n_in,
                              void* d_out, int out_size, void* d_ws, size_t ws_size,
                              hipStream_t stream) {
  const float* img = (const float*)d_in[0];
  static const int Nr[6]  = {2000, 1500, 1000, 500, 100, 10};
  static const int Kr[6]  = {12000, 2000, 1500, 1000, 500, 100};
  static const int Npd[6] = {2048, 1536, 1024, 512, 128, 128};
  static const int Kpd[6] = {12032, 2048, 1536, 1024, 512, 128};

  char* p = (char*)d_ws;
  f16* whi[6];
  f16* wlo[6];
  for (int k = 0; k < 6; ++k) {
    whi[k] = (f16*)p; p += (size_t)Npd[k] * Kpd[k] * 2;
    wlo[k] = (f16*)p; p += (size_t)Npd[k] * Kpd[k] * 2;
  }
  f16* S = (f16*)p;  p += (size_t)4096 * 12032 * 2;  // spike buffer (max width layer 0)
  float* G = (float*)p;                              // GEMM-out buffer (max 4096x2048 f32)

  PrepArgs pa;
  int nb = 0;
  for (int k = 0; k < 6; ++k) {
    pa.W[k] = (const float*)d_in[k + 1];
    pa.hi[k] = whi[k];
    pa.lo[k] = wlo[k];
    pa.Nr[k] = Nr[k]; pa.Kr[k] = Kr[k]; pa.Kp[k] = Kpd[k];
    pa.boff[k] = nb;
    nb += ((Npd[k] * Kpd[k]) >> 2) / 256;  // total4 / 256 (all divisible)
  }
  pa.boff[6] = nb;
  prep_w_all<<<nb, 256, 0, stream>>>(pa);

  enc_lif0<<<(128 * 6016 + 255) / 256, 256, 0, stream>>>(img, S);
  for (int k = 0; k < 6; ++k) {
    if (k < 2) {
      gemm_8ph<<<dim3(Npd[k] / 128, 16), dim3(512), 0, stream>>>(
          S, whi[k], wlo[k], G, Kpd[k], Npd[k]);
    } else {
      gemm_hilo<<<dim3(Npd[k] / 128, 32), dim3(256), 0, stream>>>(
          S, whi[k], wlo[k], G, Kpd[k], Npd[k]);
    }
    if (k < 5)
      li_lif<<<(128 * (Npd[k] >> 1) + 255) / 256, 256, 0, stream>>>(G, S, Npd[k]);
  }
  final_k<<<128, 64, 0, stream>>>(G, (float*)d_out);
}

// Round 5
// 558.051 us; speedup vs baseline: 1.3418x; 1.3418x over previous
//
#include <hip/hip_runtime.h>

typedef _Float16 f16;
typedef _Float16 f16x2 __attribute__((ext_vector_type(2)));
typedef _Float16 f16x4 __attribute__((ext_vector_type(4)));
typedef _Float16 f16x8 __attribute__((ext_vector_type(8)));
typedef float f32x4 __attribute__((ext_vector_type(4)));

#define KM 0.1f   // DT * TAU_MEM_INV
#define KS 0.8f   // 1 - DT * TAU_SYN_INV
#define AS1 __attribute__((address_space(1)))
#define AS3 __attribute__((address_space(3)))
#define EPS_LO 2.44140625e-4f  // 2^-12

// ---------- merged weight prep ----------
// k<=1: write interleaved W2[2*Np][Kp]: 16-row blocks alternate hi/lo.
// k>=2: separate whi/wlo (round-1 verified layout for gemm_hilo).
struct PrepArgs {
  const float* W[6];
  f16* dsth[6];
  f16* dstl[6];
  int Nr[6], Kr[6], Kp[6], Npd[6];
  int boff[7];
  int inter[6];
};

__global__ void prep_w_all(PrepArgs a) {
  int blk = blockIdx.x;
  int k = 0;
#pragma unroll
  for (int j = 0; j < 5; ++j) k += (blk >= a.boff[j + 1]) ? 1 : 0;
  int i = (blk - a.boff[k]) * 256 + threadIdx.x;
  int Kp = a.Kp[k];
  int kp4 = Kp >> 2;
  int total4 = a.Npd[k] * kp4;
  if (i >= total4) return;
  int o = i / kp4, f = (i - o * kp4) << 2;
  float w[4] = {0.f, 0.f, 0.f, 0.f};
  if (o < a.Nr[k] && f < a.Kr[k]) {  // Kr % 4 == 0 -> float4 fully in-range
    float4 t = *(const float4*)&a.W[k][(size_t)o * a.Kr[k] + f];
    w[0] = t.x; w[1] = t.y; w[2] = t.z; w[3] = t.w;
  }
  f16x4 h4, l4;
#pragma unroll
  for (int e = 0; e < 4; ++e) {
    f16 h = (f16)w[e];
    float hf = (float)h;
    if (__builtin_fabsf(hf) < 6.103515625e-05f) { h = (f16)0.f; hf = 0.f; }
    h4[e] = h;
    l4[e] = (f16)((w[e] - hf) * 4096.0f);
  }
  if (a.inter[k]) {
    int r2 = ((o >> 4) << 5) + (o & 15);  // hi block
    *(f16x4*)&a.dsth[k][(size_t)r2 * Kp + f] = h4;
    *(f16x4*)&a.dsth[k][(size_t)(r2 + 16) * Kp + f] = l4;
  } else {
    *(f16x4*)&a.dsth[k][(size_t)o * Kp + f] = h4;
    *(f16x4*)&a.dstl[k][(size_t)o * Kp + f] = l4;
  }
}

// ---------- encoder + LIF0, 2 features per thread ----------
__global__ void enc_lif0(const float* __restrict__ img, f16* __restrict__ S0) {
  int idx = blockIdx.x * 256 + threadIdx.x;
  if (idx >= 128 * 6016) return;
  int b = idx / 6016, f = (idx - b * 6016) << 1;
  float x0 = 0.f, x1 = 0.f;
  if (f < 12000) {
    float2 t = *(const float2*)&img[b * 12000 + f];
    x0 = t.x; x1 = t.y;
  }
  float ve0 = 0.f, vl0 = 0.f, il0 = 0.f;
  float ve1 = 0.f, vl1 = 0.f, il1 = 0.f;
  size_t base = (size_t)b * 12032 + f;
  for (int t = 0; t < 32; ++t) {
    ve0 = ve0 + KM * (x0 - ve0);
    ve1 = ve1 + KM * (x1 - ve1);
    float z0a = (ve0 > 1.0f) ? 1.f : 0.f;
    float z0b = (ve1 > 1.0f) ? 1.f : 0.f;
    ve0 -= z0a * ve0; ve1 -= z0b * ve1;
    float vd0 = vl0 + KM * (il0 - vl0), id0 = KS * il0;
    float vd1 = vl1 + KM * (il1 - vl1), id1 = KS * il1;
    float z1a = (vd0 > 1.0f) ? 1.f : 0.f;
    float z1b = (vd1 > 1.0f) ? 1.f : 0.f;
    vl0 = (1.f - z1a) * vd0; il0 = id0 + z0a;
    vl1 = (1.f - z1b) * vd1; il1 = id1 + z0b;
    f16x2 s; s[0] = (f16)z1a; s[1] = (f16)z1b;
    *(f16x2*)&S0[base + (size_t)t * (128 * 12032)] = s;
  }
}

// ---------- big-tile GEMM for layers 0,1: BM=256, BN=128 (W2 rows), 8 waves ----------
// C[M, Np_logical] = A[M,Kp] @ W2^T combined: W2 16-row blocks alternate hi/lo.
// Round-1 verified m97 2-barrier structure + zero-conflict 8-slot swizzle.
// Single-buffered 48 KiB LDS -> 2 blocks/CU (TLP hides the barrier drain).
__launch_bounds__(512, 4)
__global__ void gemm_big(const f16* __restrict__ A, const f16* __restrict__ B2,
                         float* __restrict__ C, int Kp, int Np) {
  __shared__ f16 sA[256 * 64];  // 32 KiB
  __shared__ f16 sB[128 * 64];  // 16 KiB
  const int tid = threadIdx.x;
  const int lane = tid & 63;
  const int wave = tid >> 6;
  const int wr = wave >> 1;   // 0..3 over M (64 rows each)
  const int wc = wave & 1;    // 0..1 over W2 rows (64 each)

  const int nx = gridDim.x;   // (2*Np)/128
  const int flat = blockIdx.y * nx + blockIdx.x;
  const int cpx = (nx * gridDim.y) >> 3;
  const int id = (flat & 7) * cpx + (flat >> 3);
  const int m0 = (id / nx) * 256;
  const int n0 = (id % nx) * 128;  // W2-row base

  f32x4 zero = {0.f, 0.f, 0.f, 0.f};
  f32x4 acc[4][4];
#pragma unroll
  for (int m = 0; m < 4; ++m)
#pragma unroll
    for (int n = 0; n < 4; ++n) acc[m][n] = zero;

  const int nkt = Kp >> 6;
  for (int kt = 0; kt < nkt; ++kt) {
    __syncthreads();
    const f16* Ab = A + (size_t)m0 * Kp + (size_t)kt * 64;
    const f16* Bb = B2 + (size_t)n0 * Kp + (size_t)kt * 64;
#pragma unroll
    for (int j = 0; j < 4; ++j) {   // A: 256 rows x 8 chunks = 2048 = 4*512
      int q = j * 512 + tid;
      int r = q >> 3, c = ((q & 7) ^ (r & 7)) * 8;
      __builtin_amdgcn_global_load_lds((const AS1 void*)(Ab + (size_t)r * Kp + c),
                                       (AS3 void*)(&sA[q * 8]), 16, 0, 0);
    }
#pragma unroll
    for (int j = 0; j < 2; ++j) {   // B: 128 rows x 8 chunks = 1024 = 2*512
      int q = j * 512 + tid;
      int r = q >> 3, c = ((q & 7) ^ (r & 7)) * 8;
      __builtin_amdgcn_global_load_lds((const AS1 void*)(Bb + (size_t)r * Kp + c),
                                       (AS3 void*)(&sB[q * 8]), 16, 0, 0);
    }
    __syncthreads();
#pragma unroll
    for (int kk = 0; kk < 2; ++kk) {
      const int lr = lane & 15;
      const int hq = lane >> 4;
      f16x8 af[4], bf[4];
#pragma unroll
      for (int m = 0; m < 4; ++m) {
        int R = wr * 64 + m * 16 + lr;
        int ch = (kk * 4 + hq) ^ (R & 7);
        af[m] = *(const f16x8*)&sA[R * 64 + ch * 8];
      }
#pragma unroll
      for (int n = 0; n < 4; ++n) {
        int R = wc * 64 + n * 16 + lr;
        int ch = (kk * 4 + hq) ^ (R & 7);
        bf[n] = *(const f16x8*)&sB[R * 64 + ch * 8];
      }
#pragma unroll
      for (int m = 0; m < 4; ++m)
#pragma unroll
        for (int n = 0; n < 4; ++n)
          acc[m][n] = __builtin_amdgcn_mfma_f32_16x16x32_f16(af[m], bf[n], acc[m][n], 0, 0, 0);
    }
  }

  // epilogue: fragment pairs (n even = hi16, n odd = lo16 of same logical cols)
  const int lr = lane & 15, lq = lane >> 4;
#pragma unroll
  for (int m = 0; m < 4; ++m)
#pragma unroll
    for (int j = 0; j < 2; ++j) {
      int col = (n0 >> 1) + wc * 32 + j * 16 + lr;
#pragma unroll
      for (int i = 0; i < 4; ++i) {
        int row = m0 + wr * 64 + m * 16 + lq * 4 + i;
        C[(size_t)row * Np + col] = acc[m][2 * j][i] + EPS_LO * acc[m][2 * j + 1][i];
      }
    }
}

// ---------- 128x128 4-wave GEMM (round-1 proven) for layers 2..5 ----------
__launch_bounds__(256, 2)
__global__ void gemm_hilo(const f16* __restrict__ A, const f16* __restrict__ Bh,
                          const f16* __restrict__ Bl, float* __restrict__ C,
                          int Kp, int Np) {
  __shared__ f16 sA[128 * 64];
  __shared__ f16 sBh[128 * 64];
  __shared__ f16 sBl[128 * 64];
  const int tid = threadIdx.x;
  const int lane = tid & 63;
  const int wave = tid >> 6;
  const int wr = wave >> 1, wc = wave & 1;

  const int nx = gridDim.x;
  const int flat = blockIdx.y * nx + blockIdx.x;
  const int cpx = (nx * gridDim.y) >> 3;
  const int id = (flat & 7) * cpx + (flat >> 3);
  const int m0 = (id / nx) * 128, n0 = (id % nx) * 128;

  f32x4 zero = {0.f, 0.f, 0.f, 0.f};
  f32x4 ah[4][4], al[4][4];
#pragma unroll
  for (int m = 0; m < 4; ++m)
#pragma unroll
    for (int n = 0; n < 4; ++n) { ah[m][n] = zero; al[m][n] = zero; }

  const int nkt = Kp >> 6;
  for (int kt = 0; kt < nkt; ++kt) {
    __syncthreads();
    const f16* Ab = A + (size_t)m0 * Kp + (size_t)kt * 64;
    const f16* Bhb = Bh + (size_t)n0 * Kp + (size_t)kt * 64;
    const f16* Blb = Bl + (size_t)n0 * Kp + (size_t)kt * 64;
#pragma unroll
    for (int j = 0; j < 4; ++j) {
      int q = j * 256 + tid;
      int r = q >> 3;
      int c0 = ((q & 7) ^ (r & 7)) * 8;
      __builtin_amdgcn_global_load_lds((const AS1 void*)(Ab + (size_t)r * Kp + c0),
                                       (AS3 void*)(&sA[q * 8]), 16, 0, 0);
      __builtin_amdgcn_global_load_lds((const AS1 void*)(Bhb + (size_t)r * Kp + c0),
                                       (AS3 void*)(&sBh[q * 8]), 16, 0, 0);
      __builtin_amdgcn_global_load_lds((const AS1 void*)(Blb + (size_t)r * Kp + c0),
                                       (AS3 void*)(&sBl[q * 8]), 16, 0, 0);
    }
    __syncthreads();
#pragma unroll
    for (int kk = 0; kk < 2; ++kk) {
      const int lr = lane & 15;
      const int hq = lane >> 4;
      f16x8 af[4], bhf[4], blf[4];
#pragma unroll
      for (int m = 0; m < 4; ++m) {
        int R = wr * 64 + m * 16 + lr;
        int ch = (kk * 4 + hq) ^ (R & 7);
        af[m] = *(const f16x8*)&sA[R * 64 + ch * 8];
      }
#pragma unroll
      for (int n = 0; n < 4; ++n) {
        int R = wc * 64 + n * 16 + lr;
        int ch = (kk * 4 + hq) ^ (R & 7);
        bhf[n] = *(const f16x8*)&sBh[R * 64 + ch * 8];
        blf[n] = *(const f16x8*)&sBl[R * 64 + ch * 8];
      }
#pragma unroll
      for (int m = 0; m < 4; ++m)
#pragma unroll
        for (int n = 0; n < 4; ++n) {
          ah[m][n] = __builtin_amdgcn_mfma_f32_16x16x32_f16(af[m], bhf[n], ah[m][n], 0, 0, 0);
          al[m][n] = __builtin_amdgcn_mfma_f32_16x16x32_f16(af[m], blf[n], al[m][n], 0, 0, 0);
        }
    }
  }
  const int lr = lane & 15, lq = lane >> 4;
#pragma unroll
  for (int m = 0; m < 4; ++m)
#pragma unroll
    for (int n = 0; n < 4; ++n) {
      int col = n0 + wc * 64 + n * 16 + lr;
#pragma unroll
      for (int i = 0; i < 4; ++i) {
        int row = m0 + wr * 64 + m * 16 + lq * 4 + i;
        C[(size_t)row * Np + col] = ah[m][n][i] + EPS_LO * al[m][n][i];
      }
    }
}

// ---------- LI_k + LIF_{k+1}, 2 neurons per thread ----------
__global__ void li_lif(const float* __restrict__ G, f16* __restrict__ Sn, int Np) {
  int np2 = Np >> 1;
  int idx = blockIdx.x * 256 + threadIdx.x;
  if (idx >= 128 * np2) return;
  int b = idx / np2, n = (idx - b * np2) << 1;
  size_t base = (size_t)b * Np + n;
  size_t stride = (size_t)128 * Np;
  float vL0 = 0.f, iL0 = 0.f, vF0 = 0.f, iF0 = 0.f;
  float vL1 = 0.f, iL1 = 0.f, vF1 = 0.f, iF1 = 0.f;
  for (int t = 0; t < 32; ++t) {
    float2 g = *(const float2*)&G[base + t * stride];
    float ij0 = iL0 + g.x, ij1 = iL1 + g.y;
    vL0 = vL0 + KM * (ij0 - vL0); iL0 = KS * ij0;
    vL1 = vL1 + KM * (ij1 - vL1); iL1 = KS * ij1;
    float vd0 = vF0 + KM * (iF0 - vF0), id0 = KS * iF0;
    float vd1 = vF1 + KM * (iF1 - vF1), id1 = KS * iF1;
    float z0 = (vd0 > 1.0f) ? 1.f : 0.f;
    float z1 = (vd1 > 1.0f) ? 1.f : 0.f;
    vF0 = (1.f - z0) * vd0; iF0 = id0 + vL0;
    vF1 = (1.f - z1) * vd1; iF1 = id1 + vL1;
    f16x2 s; s[0] = (f16)z0; s[1] = (f16)z1;
    *(f16x2*)&Sn[base + t * stride] = s;
  }
}

// ---------- LI5 scan + max over t + log_softmax ----------
__global__ void final_k(const float* __restrict__ G, float* __restrict__ out) {
  int b = blockIdx.x;
  int n = threadIdx.x;
  float vL = 0.f, iL = 0.f, mx = -3.4e38f;
  for (int t = 0; t < 32; ++t) {
    float g = G[(size_t)(t * 128 + b) * 128 + n];
    float ij = iL + g;
    vL = vL + KM * (ij - vL);
    iL = KS * ij;
    mx = fmaxf(mx, vL);
  }
  float v = (n < 10) ? mx : -3.4e38f;
  float M = v;
#pragma unroll
  for (int s = 1; s < 16; s <<= 1) M = fmaxf(M, __shfl_xor(M, s));
  float e = (n < 10) ? expf(v - M) : 0.f;
  float sum = e;
#pragma unroll
  for (int s = 1; s < 16; s <<= 1) sum += __shfl_xor(sum, s);
  if (n < 10) out[b * 10 + n] = v - M - logf(sum);
}

extern "C" void kernel_launch(void* const* d_in, const int* in_sizes, int n_in,
                              void* d_out, int out_size, void* d_ws, size_t ws_size,
                              hipStream_t stream) {
  const float* img = (const float*)d_in[0];
  static const int Nr[6]  = {2000, 1500, 1000, 500, 100, 10};
  static const int Kr[6]  = {12000, 2000, 1500, 1000, 500, 100};
  static const int Npd[6] = {2048, 1536, 1024, 512, 128, 128};
  static const int Kpd[6] = {12032, 2048, 1536, 1024, 512, 128};

  char* p = (char*)d_ws;
  f16* wa[6];  // k<=1: W2 interleaved [2*Npd][Kpd]; k>=2: whi
  f16* wb[6];  // k>=2: wlo (k<=1: unused, aliases wa)
  for (int k = 0; k < 6; ++k) {
    if (k < 2) {
      wa[k] = (f16*)p; wb[k] = wa[k];
      p += (size_t)2 * Npd[k] * Kpd[k] * 2;
    } else {
      wa[k] = (f16*)p; p += (size_t)Npd[k] * Kpd[k] * 2;
      wb[k] = (f16*)p; p += (size_t)Npd[k] * Kpd[k] * 2;
    }
  }
  f16* S = (f16*)p;  p += (size_t)4096 * 12032 * 2;  // spike buffer (max width layer 0)
  float* G = (float*)p;                              // GEMM-out buffer (max 4096x2048 f32)

  PrepArgs pa;
  int nb = 0;
  for (int k = 0; k < 6; ++k) {
    pa.W[k] = (const float*)d_in[k + 1];
    pa.dsth[k] = wa[k];
    pa.dstl[k] = wb[k];
    pa.Nr[k] = Nr[k]; pa.Kr[k] = Kr[k]; pa.Kp[k] = Kpd[k]; pa.Npd[k] = Npd[k];
    pa.inter[k] = (k < 2) ? 1 : 0;
    pa.boff[k] = nb;
    nb += ((Npd[k] * Kpd[k]) >> 2) / 256;  // exact for all layers
  }
  pa.boff[6] = nb;
  prep_w_all<<<nb, 256, 0, stream>>>(pa);

  enc_lif0<<<(128 * 6016 + 255) / 256, 256, 0, stream>>>(img, S);
  for (int k = 0; k < 6; ++k) {
    if (k < 2) {
      gemm_big<<<dim3(2 * Npd[k] / 128, 16), dim3(512), 0, stream>>>(
          S, wa[k], G, Kpd[k], Npd[k]);
    } else {
      gemm_hilo<<<dim3(Npd[k] / 128, 32), dim3(256), 0, stream>>>(
          S, wa[k], wb[k], G, Kpd[k], Npd[k]);
    }
    if (k < 5)
      li_lif<<<(128 * (Npd[k] >> 1) + 255) / 256, 256, 0, stream>>>(G, S, Npd[k]);
  }
  final_k<<<128, 64, 0, stream>>>(G, (float*)d_out);
}